// Round 6
// baseline (3014.745 us; speedup 1.0000x reference)
//
#include <hip/hip_runtime.h>
#include <hip/hip_bf16.h>
#include <math.h>

#define HW 4096
#define NB 8
#define NT 16
#define HB 262144L
#define NBLK 512

typedef unsigned short u16;
typedef __attribute__((ext_vector_type(8))) short bf16x8;
typedef __attribute__((ext_vector_type(4))) float f32x4;

__device__ __forceinline__ float sigmoid_f(float x) {
  return 1.f / (1.f + __expf(-x));
}
__device__ __forceinline__ float tanh_f(float x) {
  float ax = fabsf(x);
  float e = __expf(2.f * ax);
  float t = 1.f - 2.f / (e + 1.f);
  return copysignf(t, x);
}
__device__ __forceinline__ u16 f2b(float v) {
  __hip_bfloat16 h = __float2bfloat16(v);
  return *(u16*)&h;
}

// ---- weight transform: w[256][CIN][3][3] f32 -> wtB[chunk][tap][gate][32ci] bf16
__global__ void transform_wB(const float* __restrict__ w, u16* __restrict__ wtB,
                             int CIN, int cinbase, int nch) {
  int idx = blockIdx.x * 256 + threadIdx.x;
  int total = nch * 9 * 256 * 32;
  if (idx >= total) return;
  int ci32 = idx & 31;
  int rest = idx >> 5;
  int gate = rest & 255;
  rest >>= 8;
  int tap = rest % 9;
  int chunk = rest / 9;
  int cin = cinbase + chunk * 32 + ci32;
  wtB[idx] = f2b(w[((size_t)gate * CIN + cin) * 9 + tap]);
}

// ---- layer0 xin-part weights: wtA[gate][32k] bf16, k = ci*9+tap (ci<3), pad 0
__global__ void transform_wA(const float* __restrict__ w0, u16* __restrict__ wtA) {
  int idx = blockIdx.x * 256 + threadIdx.x;  // 8192
  if (idx >= 8192) return;
  int k = idx & 31, gate = idx >> 5;
  u16 v = 0;
  if (k < 27) {
    int ci = (k >= 18) + (k >= 9);
    int tap = k - ci * 9;
    v = f2b(w0[((size_t)gate * 67 + ci) * 9 + tap]);
  }
  wtA[idx] = v;
}

// ---- attention reduce: per (b,t,c) avg & max over HW ----
__global__ void att_reduce(const float* __restrict__ x, float* __restrict__ avg,
                           float* __restrict__ mx) {
  int btc = blockIdx.x;  // 384
  const float* p = x + (size_t)btc * HW;
  float s = 0.f, m = -INFINITY;
  for (int i = threadIdx.x; i < HW; i += 256) {
    float v = p[i];
    s += v;
    m = fmaxf(m, v);
  }
  #pragma unroll
  for (int off = 32; off; off >>= 1) {
    s += __shfl_down(s, off, 64);
    m = fmaxf(m, __shfl_down(m, off, 64));
  }
  __shared__ float ss[4], sm[4];
  int wid = threadIdx.x >> 6, lane = threadIdx.x & 63;
  if (lane == 0) { ss[wid] = s; sm[wid] = m; }
  __syncthreads();
  if (threadIdx.x == 0) {
    avg[btc] = (ss[0] + ss[1] + ss[2] + ss[3]) * (1.f / 4096.f);
    mx[btc]  = fmaxf(fmaxf(sm[0], sm[1]), fmaxf(sm[2], sm[3]));
  }
}

// ---- attention apply -> xin_t[bt][pix][4ci] bf16 (channel-last, slot3 = 0) ----
__global__ void att_apply(const float* __restrict__ x, const float* __restrict__ avg,
                          const float* __restrict__ mx, const float* __restrict__ w1,
                          const float* __restrict__ w2, u16* __restrict__ xin_t) {
  size_t i = (size_t)blockIdx.x * 256 + threadIdx.x;  // 1,572,864 = (bt, c, pix)
  int pix = (int)(i & 4095);
  int c   = (int)((i >> 12) % 3);
  int bt  = (int)(i / (3 * HW));
  const float* a = avg + bt * 3;
  const float* m = mx + bt * 3;
  float ra = fmaxf(0.f, w1[0] * a[0] + w1[1] * a[1] + w1[2] * a[2]);
  float rm = fmaxf(0.f, w1[0] * m[0] + w1[1] * m[1] + w1[2] * m[2]);
  float sc = sigmoid_f(w2[c] * (ra + rm));
  xin_t[((size_t)bt * HW + pix) * 4 + c] = f2b(x[i] * sc);
}

// ---- per-role parameter set for one conv+LSTM step ----
struct RoleP {
  const u16* a0; long a0_bs; const u16* wtA;   // layer0 xin path (a0 null otherwise)
  const u16* s0; long s0_bs; int s0_ch;        // h-style source 0 ([b][ch][4096][32])
  const u16* s1; long s1_bs; int s1_ch;        // h-style source 1
  const u16* wtB; const float* bias;
  float* c_t;                                  // [b][4096][64] f32
  u16* h_t;                                    // [b][2][4096][32] bf16
  float* out_f32; long out_bs;                 // [b][t][hc][4096] f32 (or null)
};

// ---- persistent-kernel parameter set ----
struct PP {
  const u16* xin; const u16* wtA;
  const u16* wtB0; const float* b0; float* c0; u16* h0a; u16* h0b;
  const u16* wtB1; const float* b1; float* c1; u16* h1a; u16* h1b;
  const u16* zb; float* out;
  unsigned* bar;                               // [0]=arrival count, [1]=generation
};

// ---- staging: chunk tile = 4 input rows x 66 sites x 32 ch, granule = 16 B ----
__device__ __forceinline__ void dma_site(const u16* sp, u16* bufn, int idx,
                                         const u16* zb, int r0g) {
  int site = idx >> 2, sub = idx & 3;
  int r = site / 66, cc = site - r * 66;
  int gr = r0g - 1 + r, gc = cc - 1;
  const u16* g = (site < 264 && (unsigned)gr < 64u && (unsigned)gc < 64u)
               ? sp + (size_t)(gr * 64 + gc) * 32 + sub * 8
               : zb;                            // OOB / pad lanes read the zero page
  u16* l = bufn + (size_t)(idx & ~63) * 8;      // wave-uniform LDS base; HW adds lane*16
  __builtin_amdgcn_global_load_lds(
      (const __attribute__((address_space(1))) unsigned int*)g,
      (__attribute__((address_space(3))) unsigned int*)l, 16, 0, 0);
}

__device__ __forceinline__ void dma_chunk(const u16* sp, u16* bufn, const u16* zb,
                                          int r0g, int tid) {
  #pragma unroll
  for (int it = 0; it < 4; ++it) dma_site(sp, bufn, it * 256 + tid, zb, r0g);
  if (tid < 64) dma_site(sp, bufn, 1024 + tid, zb, r0g);   // tail pads to 1088
}

#define BQ_LOAD(S, BASE, TP)                                              \
  { _Pragma("unroll")                                                     \
    for (int _g = 0; _g < 4; ++_g)                                        \
      bq[S][_g] = *(const bf16x8*)((BASE) + (TP) * 8192 + _g * 2048); }

// one 9-tap chunk; PAR = tap parity at chunk start (B ring-2, distance-1)
// wave tile: mt 0..7 (128 px = 2 rows) x gt 0..3 (64 gates) -> 32 MFMA/tap
template <int PAR>
__device__ __forceinline__ void chunk_compute(const u16* bufc, const u16* bpc,
                                              const u16* bpn, bool more,
                                              bf16x8 (&bq)[2][4], f32x4 (&acc)[8][4],
                                              int abase) {
  #pragma unroll
  for (int tap = 0; tap < 9; ++tap) {
    if (tap < 8) { BQ_LOAD((tap + 1 + PAR) & 1, bpc, tap + 1) }
    else if (more) { BQ_LOAD((1 + PAR) & 1, bpn, 0) }
    const int dy = tap / 3, dx = tap - dy * 3;
    bf16x8 av[8];
    #pragma unroll
    for (int mt = 0; mt < 8; ++mt)
      av[mt] = *(const bf16x8*)(bufc + abase + ((mt >> 2) + dy) * 2112 + dx * 32 + (mt & 3) * 512);
    #pragma unroll
    for (int mt = 0; mt < 8; ++mt)
      #pragma unroll
      for (int gt = 0; gt < 4; ++gt)
        acc[mt][gt] = __builtin_amdgcn_mfma_f32_16x16x32_bf16(
            av[mt], bq[(tap + PAR) & 1][gt], acc[mt][gt], 0, 0, 0);
  }
}

#define SP_SET(CG)                                                           \
  sp = ((CG) < P.s0_ch)                                                      \
     ? P.s0 + (size_t)b * P.s0_bs + (size_t)(CG) * 131072                    \
     : P.s1 + (size_t)b * P.s1_bs + (size_t)((CG) - P.s0_ch) * 131072;

// ---- one conv+LSTM step for a 2-row x 256-gate tile ----
__device__ __forceinline__ void conv_body(const RoleP& P, const u16* zb,
                                          u16 (&smem)[2][8704], u16 (&xtile)[4096],
                                          int r0g, int b, int tid) {
  const int gc = tid >> 6, lane = tid & 63;
  const int n = lane & 15, q = lane >> 4;
  const int abase = n * 32 + q * 8;
  const int ntot = P.s0_ch + P.s1_ch;           // 2 (layer0) or 4 (layer1), even

  f32x4 acc[8][4];
  #pragma unroll
  for (int mt = 0; mt < 8; ++mt)
    #pragma unroll
    for (int gt = 0; gt < 4; ++gt)
      acc[mt][gt] = (f32x4){0.f, 0.f, 0.f, 0.f};

  const u16* bp0 = P.wtB + (size_t)(gc * 16 + n) * 32 + q * 8;
  bf16x8 bq[2][4];
  const u16* sp;

  // ---- prologue: chunk-0 DMA + B tap-0, overlap with layer-0 xin staging ----
  SP_SET(0);
  dma_chunk(sp, &smem[0][0], zb, r0g, tid);
  BQ_LOAD(0, bp0, 0)
  if (P.a0) {
    const u16* ap = P.a0 + (size_t)b * P.a0_bs;
    for (int idx = tid; idx < 4096; idx += 256) {
      int row = idx >> 11, rest = idx & 2047;
      int k = rest & 31, px = rest >> 5;
      u16 v = 0;
      if (k < 27) {
        int ci = (k >= 18) + (k >= 9);
        int tap = k - ci * 9;
        int dy = (tap >= 6) ? 2 : (tap >= 3 ? 1 : 0);
        int dx = tap - dy * 3;
        int gr = r0g + row - 1 + dy, gcl = px - 1 + dx;
        if ((unsigned)gr < 64u && (unsigned)gcl < 64u)
          v = ap[((size_t)(gr * 64 + gcl)) * 4 + ci];
      }
      xtile[idx] = v;
    }
  }
  __syncthreads();   // drains DMA (vmcnt0) + xtile writes
  if (P.a0) {
    bf16x8 bxa[4], axv[8];
    #pragma unroll
    for (int gt = 0; gt < 4; ++gt)
      bxa[gt] = *(const bf16x8*)(P.wtA + ((gc + 4 * gt) * 16 + n) * 32 + q * 8);
    #pragma unroll
    for (int mt = 0; mt < 8; ++mt)
      axv[mt] = *(const bf16x8*)(xtile + (mt >> 2) * 2048 + ((mt & 3) * 16 + n) * 32 + q * 8);
    #pragma unroll
    for (int mt = 0; mt < 8; ++mt)
      #pragma unroll
      for (int gt = 0; gt < 4; ++gt)
        acc[mt][gt] = __builtin_amdgcn_mfma_f32_16x16x32_bf16(axv[mt], bxa[gt], acc[mt][gt], 0, 0, 0);
  }

  // ---- main chunk loop, unrolled x2 (compile-time ring parity) ----
  int cur = 0;
  for (int cg = 0; cg < ntot; cg += 2) {
    {   // even-parity chunk: cg
      SP_SET(cg + 1);
      dma_chunk(sp, &smem[cur ^ 1][0], zb, r0g, tid);
      chunk_compute<0>(&smem[cur][0], bp0 + (size_t)cg * 73728,
                       bp0 + (size_t)(cg + 1) * 73728, true, bq, acc, abase);
      __syncthreads();
      cur ^= 1;
    }
    {   // odd-parity chunk: cg+1
      bool more = (cg + 2 < ntot);
      if (more) {
        SP_SET(cg + 2);
        dma_chunk(sp, &smem[cur ^ 1][0], zb, r0g, tid);
      }
      chunk_compute<1>(&smem[cur][0], bp0 + (size_t)(cg + 1) * 73728,
                       bp0 + (size_t)(cg + 2) * 73728, more, bq, acc, abase);
      __syncthreads();
      cur ^= 1;
    }
  }

  // ---- LSTM pointwise epilogue (lane-local: hc = 16*gc+n; gt = i,f,o,g) ----
  const int hc = gc * 16 + n;
  const float bi = P.bias[hc], bfv = P.bias[64 + hc], bo = P.bias[128 + hc], bg = P.bias[192 + hc];
  float* cB = P.c_t + ((size_t)b * HW + r0g * 64) * 64 + hc;
  u16*   hB = P.h_t + (size_t)b * 262144 + (size_t)(hc >> 5) * 131072
            + (size_t)(r0g * 64) * 32 + (hc & 31);
  float* tbuf = (float*)&smem[0][0];            // 128 px x 65 floats (33,280 B)
  #pragma unroll
  for (int mt = 0; mt < 8; ++mt) {
    #pragma unroll
    for (int reg = 0; reg < 4; ++reg) {
      int px = mt * 16 + q * 4 + reg;           // 0..127 over both rows
      float xi = acc[mt][0][reg] + bi;
      float xf = acc[mt][1][reg] + bfv;
      float xo = acc[mt][2][reg] + bo;
      float xg = acc[mt][3][reg] + bg;
      float ii = sigmoid_f(xi), ff = sigmoid_f(xf), oo = sigmoid_f(xo), gg = tanh_f(xg);
      float cold = cB[(size_t)px * 64];
      float cnew = ff * cold + ii * gg;
      float hnew = oo * tanh_f(cnew);
      cB[(size_t)px * 64] = cnew;
      hB[(size_t)px * 32] = f2b(hnew);
      if (P.out_f32) tbuf[px * 65 + hc] = hnew;
    }
  }
  if (P.out_f32) {   // coalesced out write via LDS transpose (both rows)
    __syncthreads();
    int hc2 = tid >> 2, qq = tid & 3;
    #pragma unroll
    for (int rw = 0; rw < 2; ++rw) {
      float* orow = P.out_f32 + (size_t)b * P.out_bs + (size_t)hc2 * HW + (r0g + rw) * 64;
      #pragma unroll
      for (int j = 0; j < 4; ++j) {
        int p0x = qq * 4 + j * 16;
        float4 v = make_float4(tbuf[(rw * 64 + p0x + 0) * 65 + hc2],
                               tbuf[(rw * 64 + p0x + 1) * 65 + hc2],
                               tbuf[(rw * 64 + p0x + 2) * 65 + hc2],
                               tbuf[(rw * 64 + p0x + 3) * 65 + hc2]);
        *(float4*)(orow + p0x) = v;
      }
    }
  }
}

// ---- manual grid barrier: sense-free generation counter, agent-scope atomics ----
// bar[0] = arrival count (reset by last arriver), bar[1] = generation.
// Safety valve: bounded spin -> on residency bug we fail correctness, not hang.
__device__ __forceinline__ void grid_barrier(unsigned* bar, unsigned step) {
  __syncthreads();
  if (threadIdx.x == 0) {
    __threadfence();   // release h/c/out stores device-wide (agent scope)
    unsigned old = __hip_atomic_fetch_add(&bar[0], 1u, __ATOMIC_ACQ_REL,
                                          __HIP_MEMORY_SCOPE_AGENT);
    if (old == NBLK - 1u) {
      __hip_atomic_store(&bar[0], 0u, __ATOMIC_RELAXED, __HIP_MEMORY_SCOPE_AGENT);
      __hip_atomic_store(&bar[1], step + 1u, __ATOMIC_RELEASE, __HIP_MEMORY_SCOPE_AGENT);
    } else {
      long spins = 0;
      while (__hip_atomic_load(&bar[1], __ATOMIC_ACQUIRE,
                               __HIP_MEMORY_SCOPE_AGENT) <= step) {
        __builtin_amdgcn_s_sleep(2);
        if (++spins > 2000000L) break;   // ~0.3 s: terminate instead of hanging
      }
    }
    __threadfence();   // acquire side: invalidate stale cached lines
  }
  __syncthreads();
}

// ---- persistent kernel: whole 17-step recurrence in one plain launch ----
// 512 blocks = 2/CU (guaranteed: launch_bounds(256,2) caps VGPR at 256; LDS 43KB
// allows 3/CU). role = bid&1; tile = bid>>1 -> (b, row-pair).
// Step s: role0 computes layer0[t=s] (s<16), role1 computes layer1[t=s-1] (s>0).
__global__ __launch_bounds__(256, 2) void conv_persist(PP pp) {
  __shared__ __align__(16) u16 smem[2][8704];
  __shared__ __align__(16) u16 xtile[4096];
  const int bid = blockIdx.x;
  const int role = bid & 1, tile = bid >> 1;
  const int r0g = (tile & 31) * 2, b = tile >> 5;
  const int tid = threadIdx.x;

  for (int s = 0; s <= NT; ++s) {
    const bool active = role ? (s > 0) : (s < NT);
    if (active) {
      const int t = role ? (s - 1) : s;
      RoleP P;
      if (!role) {
        P.a0 = pp.xin + (size_t)t * 16384; P.a0_bs = (long)NT * 16384; P.wtA = pp.wtA;
        P.s0 = (t == 0) ? pp.zb : ((t & 1) ? pp.h0a : pp.h0b);
        P.s0_bs = (t == 0) ? 0L : HB; P.s0_ch = 2;
        P.s1 = pp.zb; P.s1_bs = 0L; P.s1_ch = 0;
        P.wtB = pp.wtB0; P.bias = pp.b0; P.c_t = pp.c0;
        P.h_t = (t & 1) ? pp.h0b : pp.h0a;
        P.out_f32 = (float*)0; P.out_bs = 0L;
      } else {
        P.a0 = (const u16*)0; P.a0_bs = 0L; P.wtA = (const u16*)0;
        P.s0 = (t & 1) ? pp.h0b : pp.h0a;     // h0[t], written at step s-1
        P.s0_bs = HB; P.s0_ch = 2;
        P.s1 = (t == 0) ? pp.zb : ((t & 1) ? pp.h1a : pp.h1b);
        P.s1_bs = (t == 0) ? 0L : HB; P.s1_ch = 2;
        P.wtB = pp.wtB1; P.bias = pp.b1; P.c_t = pp.c1;
        P.h_t = (t & 1) ? pp.h1b : pp.h1a;
        P.out_f32 = pp.out + (size_t)t * 262144; P.out_bs = (long)NT * 262144;
      }
      conv_body(P, pp.zb, smem, xtile, r0g, b, tid);
    }
    if (s < NT) grid_barrier(pp.bar, (unsigned)s);   // last step: stream order suffices
  }
}

// ---- h1 final state: flat copy of out1[:, T-1] ----
__global__ void h1_final(const float* __restrict__ out1, float* __restrict__ dst) {
  size_t i = (size_t)blockIdx.x * 256 + threadIdx.x;  // 2,097,152
  size_t b = i >> 18, rem = i & 262143;
  dst[i] = out1[(b * NT + (NT - 1)) * 262144 + rem];
}

// ---- c1 final state: transpose [b][pix][hc] f32 -> [b][hc][pix] f32 ----
__global__ void c1_final(const float* __restrict__ c_t, float* __restrict__ dst) {
  __shared__ float t[64][65];
  int pb = blockIdx.x, b = blockIdx.y;
  int tx = threadIdx.x & 63, ty = threadIdx.x >> 6;
  for (int i = 0; i < 16; ++i) {
    int p = i * 4 + ty;
    t[p][tx] = c_t[((size_t)b * HW + pb * 64 + p) * 64 + tx];
  }
  __syncthreads();
  for (int i = 0; i < 16; ++i) {
    int hcv = i * 4 + ty;
    dst[(size_t)b * 262144 + (size_t)hcv * HW + pb * 64 + tx] = t[tx][hcv];
  }
}

extern "C" void kernel_launch(void* const* d_in, const int* in_sizes, int n_in,
                              void* d_out, int out_size, void* d_ws, size_t ws_size,
                              hipStream_t stream) {
  const float* x      = (const float*)d_in[0];
  const float* att_w1 = (const float*)d_in[1];
  const float* att_w2 = (const float*)d_in[2];
  const float* w0     = (const float*)d_in[3];
  const float* b0     = (const float*)d_in[4];
  const float* w1     = (const float*)d_in[5];
  const float* b1     = (const float*)d_in[6];
  float* out = (float*)d_out;
  char* ws = (char*)d_ws;

  // workspace layout (byte offsets, all 16B-aligned)
  u16*   xin_t = (u16*)(ws + 0);             // [8][16][4096][4] bf16, 4,194,304 B
  u16*   h0a   = (u16*)(ws + 4194304);       // [8][2][4096][32] bf16
  u16*   h0b   = (u16*)(ws + 8388608);
  u16*   h1a   = (u16*)(ws + 12582912);
  u16*   h1b   = (u16*)(ws + 16777216);
  u16*   zb    = (u16*)(ws + 20971520);      // 262,144 bf16 zeros (bstride 0)
  u16*   wtA0  = (u16*)(ws + 21495808);      // [256][32] bf16
  u16*   wtB0  = (u16*)(ws + 21512192);      // [2][9][256][32] bf16
  u16*   wtB1  = (u16*)(ws + 21807104);      // [4][9][256][32] bf16
  float* c0_t  = (float*)(ws + 22396928);    // [8][4096][64] f32
  float* c1_t  = (float*)(ws + 30785536);
  float* avg   = (float*)(ws + 39174144);    // 384 floats
  float* mxb   = (float*)(ws + 39175680);    // 384 floats
  unsigned* bar = (unsigned*)(ws + 39177216); // grid-barrier state (64 B)
  if (ws_size < 39177280u) return;

  hipMemsetAsync(xin_t, 0, 4194304, stream);       // zeros slot ci=3
  hipMemsetAsync(zb, 0, 524288, stream);
  hipMemsetAsync(c0_t, 0, 8388608, stream);
  hipMemsetAsync(c1_t, 0, 8388608, stream);
  hipMemsetAsync(bar, 0, 64, stream);

  transform_wA<<<32, 256, 0, stream>>>(w0, wtA0);
  transform_wB<<<576, 256, 0, stream>>>(w0, wtB0, 67, 3, 2);
  transform_wB<<<1152, 256, 0, stream>>>(w1, wtB1, 128, 0, 4);
  att_reduce<<<NB * NT * 3, 256, 0, stream>>>(x, avg, mxb);
  att_apply<<<1572864 / 256, 256, 0, stream>>>(x, avg, mxb, att_w1, att_w2, xin_t);

  // ---- persistent path: one plain (graph-capture-safe) launch ----
  PP pp;
  pp.xin = xin_t; pp.wtA = wtA0;
  pp.wtB0 = wtB0; pp.b0 = b0; pp.c0 = c0_t; pp.h0a = h0a; pp.h0b = h0b;
  pp.wtB1 = wtB1; pp.b1 = b1; pp.c1 = c1_t; pp.h1a = h1a; pp.h1b = h1b;
  pp.zb = zb; pp.out = out; pp.bar = bar;
  conv_persist<<<NBLK, 256, 0, stream>>>(pp);

  h1_final<<<8192, 256, 0, stream>>>(out, out + 33554432);
  c1_final<<<dim3(64, 8), 256, 0, stream>>>(c1_t, out + 35651584);
}